// Round 11
// baseline (2493.905 us; speedup 1.0000x reference)
//
#include <hip/hip_runtime.h>

// Overlapped pipeline: k_init -> k_feat_scan (fused producer/consumer) -> k_out.
// T=1024, B=256, D=64, H=128, fp32. Z = d_ws (T*B*H fp32).
//
// k_feat_scan: 512 blocks x 512 thr. EVEN blocks = scan (R10-verbatim numerics,
// 1 batch elem each), ODD blocks = feat producer (R0-bit-exact MFMA, 8-wave
// column-split, 16 tiles each, iteration-major: iteration it completes
// t in [64it,64it+64) across all blocks). Scan consumes z via device-scope
// atomic loads gated by per-iteration counters (feat: __threadfence +
// atomicAdd signal per wave; scan: thread0 polls once per 64 steps).
// Flags live in Z slot t=1023: feat redirects z_1023 to y-scratch (out
// overwrites y later), scan reads z_1023 from there and skips the never-read
// h_1024 store. k_init zeroes flags each launch (no cross-launch state).
// Interleaved block IDs guarantee role mixing on CUs; feat never waits ->
// deadlock-free under any dispatch order. Out stays a separate launch
// (fusing it has an adversarial-schedule deadlock via LDS packing).

#define T_SEQ 1024
#define B_SZ  256
#define D_IN  64
#define H_DIM 128

#define FLAGS_OFF  ((long)1023 * 256 * 128)   // float offset of Z slot t=1023
#define FEAT_ITERS 16                          // 16 iters x 64 t each
#define SIG_PER_ITER 2048                      // 256 feat blocks x 8 waves

typedef __attribute__((ext_vector_type(8))) _Float16 half8;
typedef __attribute__((ext_vector_type(4))) _Float16 half4;
typedef __attribute__((ext_vector_type(4))) float f32x4;

__device__ __forceinline__ float fast_tanh(float x) {
  float ax = __builtin_fabsf(x);
  float e  = __builtin_amdgcn_exp2f(ax * -2.8853900817779268f); // -2*log2(e)
  float r  = (1.0f - e) * __builtin_amdgcn_rcpf(1.0f + e);
  return __builtin_copysignf(r, x);
}

// barrier waiting ONLY lgkmcnt (LDS): vm=63, exp=7, lgkm=0 -> imm 0xC07F
__device__ __forceinline__ void barrier_lds_only() {
  __asm__ __volatile__("" ::: "memory");
  __builtin_amdgcn_s_waitcnt(0xC07F);
  __builtin_amdgcn_s_barrier();
  __asm__ __volatile__("" ::: "memory");
}

__device__ __forceinline__ half8 pack_h8(float4 a, float4 b) {
  half8 s = { (_Float16)a.x, (_Float16)a.y, (_Float16)a.z, (_Float16)a.w,
              (_Float16)b.x, (_Float16)b.y, (_Float16)b.z, (_Float16)b.w };
  return s;
}

__device__ __forceinline__ float add_xor1(float x) {
  int v = __builtin_amdgcn_mov_dpp(__float_as_int(x), 0xB1, 0xF, 0xF, true);
  return x + __int_as_float(v);
}
__device__ __forceinline__ float add_xor2(float x) {
  int v = __builtin_amdgcn_mov_dpp(__float_as_int(x), 0x4E, 0xF, 0xF, true);
  return x + __int_as_float(v);
}
__device__ __forceinline__ float dot4(float4 w, float4 h) {
  return fmaf(w.x, h.x, fmaf(w.y, h.y, fmaf(w.z, h.z, w.w * h.w)));
}

// ---------------------------------------------------------------------------
// k_init: zero the iteration counters (flags) — every launch, no stale state.
// ---------------------------------------------------------------------------
__global__ void k_init(float* __restrict__ Z) {
  if (threadIdx.x < FEAT_ITERS)
    ((int*)(Z + FLAGS_OFF))[threadIdx.x] = 0;
}

// ---------------------------------------------------------------------------
// k_feat_scan: even blocks = scan, odd blocks = feat producer.
// ---------------------------------------------------------------------------
#define WI_S 136
#define XT_S 72
#define FM_S 136

__global__ __launch_bounds__(512, 1) void k_feat_scan(
    const float* __restrict__ x,   const float* __restrict__ Wx,
    const float* __restrict__ bx,  const float* __restrict__ Wih,
    const float* __restrict__ bih, const float* __restrict__ Whh,
    const float* __restrict__ bhh, float* __restrict__ Z,
    float* __restrict__ yz)
{
  // union LDS (every block allocates all; total ~63.1 KB -> 2 blocks/CU fit)
  __shared__ __align__(16) _Float16 wi_l[128 * WI_S]; // 34816 B (feat)
  __shared__ __align__(16) _Float16 xt_l[64 * XT_S];  //  9216 B (feat)
  __shared__ __align__(16) _Float16 fm_l[64 * FM_S];  // 17408 B (feat)
  __shared__ __align__(16) float    hbuf[2][208];     //  1664 B (scan)

  int* iterCnt = (int*)(Z + FLAGS_OFF);
  const int tid = threadIdx.x;

  if ((blockIdx.x & 1) == 0) {
    // ================= scan (R10-verbatim numerics) =================
    const int b   = blockIdx.x >> 1;
    const int j   = tid >> 2;      // 0..127  (row)
    const int ks  = tid & 3;       // 0..3    (k-slice)
    const int k0  = ks * 32;
    const int k0p = ks * 56;       // padded base

    __builtin_amdgcn_s_setprio(1);

    float4 w[8];
#pragma unroll
    for (int m = 0; m < 8; ++m)
      w[m] = *(const float4*)(Whh + j*H_DIM + k0 + m*4);

    if (tid < 128) hbuf[0][tid + ((tid >> 5) * 24)] = 0.f;

    const bool writer = (ks == 0);
    const int  jp     = j + ((j >> 5) * 24);
    float* zp  = Z  + b*H_DIM + j;
    float* yzp = yz + b*H_DIM + j;     // feat-redirected z_1023 location

    // wait for feat iteration k (t in [64k, 64k+64)) to be complete
    auto poll = [&](int k) {
      if (tid == 0) {
        while ((unsigned)atomicAdd(&iterCnt[k], 0) < (unsigned)SIG_PER_ITER)
          __builtin_amdgcn_s_sleep(8);
      }
      barrier_lds_only();            // all waves gate on thread0's wave
    };

    poll(0);                         // covers t = 0..63
    float zbuf[8];
#pragma unroll
    for (int i = 0; i < 8; ++i)
      zbuf[i] = writer ? atomicAdd(zp + (long)i * 32768, 0.0f) : 0.f;

    barrier_lds_only();

    for (int tb = 0; tb < T_SEQ; tb += 8) {
      if (tb && ((tb + 8) & 63) == 0) {      // needIt changes every 64 steps
        const int ni = (tb + 15) >> 6;
        if (ni < FEAT_ITERS) poll(ni);
      }
#pragma unroll
      for (int u = 0; u < 8; ++u) {
        const int t = tb + u;
        const float* h = hbuf[t & 1] + k0p;
        float4 h0 = *(const float4*)(h);
        float4 h1 = *(const float4*)(h + 4);
        float4 h2 = *(const float4*)(h + 8);
        float4 h3 = *(const float4*)(h + 12);
        float4 h4 = *(const float4*)(h + 16);
        float4 h5 = *(const float4*)(h + 20);
        float4 h6 = *(const float4*)(h + 24);
        float4 h7 = *(const float4*)(h + 28);

        float p0 = dot4(w[0], h0);
        float p1 = dot4(w[1], h1);
        float p2 = dot4(w[2], h2);
        float p3 = dot4(w[3], h3);
        float p4 = dot4(w[4], h4);
        float p5 = dot4(w[5], h5);
        float p6 = dot4(w[6], h6);
        float p7 = dot4(w[7], h7);
        float a = ((p0 + p1) + (p2 + p3)) + ((p4 + p5) + (p6 + p7));

        a = add_xor1(a);
        a = add_xor2(a);

        if (writer) {
          float v  = a + zbuf[u];
          float hn = fast_tanh(v);
          hbuf[(t & 1) ^ 1][jp] = hn;
          if (t != 1023) zp[(long)t * 32768] = hn;   // h_1024 never read
          const int tn = t + 8;
          zbuf[u] = (tn < 1023) ? atomicAdd(zp + (long)tn * 32768, 0.0f)
                  : ((tn == 1023) ? atomicAdd(yzp, 0.0f) : 0.f);
        }
        barrier_lds_only();
      }
    }

  } else {
    // ========= feat producer (8-wave column-split, R0-bit-exact) =========
    const int B  = blockIdx.x >> 1;     // 0..255
    const int l  = tid & 63;
    const int w8 = tid >> 6;            // wave 0..7
    const int ln = l & 15;
    const int kg = l >> 4;
    const int rg = w8 & 3;              // row group (16 rows)
    const int cg = w8 >> 2;             // col group (4 of 8 nt)

    {
      const float4* w4 = (const float4*)Wih;     // 4096 float4
#pragma unroll
      for (int p = 0; p < 8; ++p) {
        int f = tid + p * 512;
        int row = f >> 5, kc = (f & 31) * 4;
        float4 v = w4[f];
        half4 s = { (_Float16)v.x, (_Float16)v.y, (_Float16)v.z, (_Float16)v.w };
        *(half4*)&wi_l[row * WI_S + kc] = s;
      }
    }
    half8 wxr[4][2];
    float bx_r[4], b2_r[4];
#pragma unroll
    for (int nt = 0; nt < 4; ++nt) {
      const int gnt = cg*4 + nt;
#pragma unroll
      for (int kf = 0; kf < 2; ++kf) {
        const float* wp = Wx + (gnt*16 + ln) * D_IN + kf*32 + kg*8;
        wxr[nt][kf] = pack_h8(*(const float4*)wp, *(const float4*)(wp + 4));
      }
      bx_r[nt] = bx[gnt*16 + ln];
      b2_r[nt] = bih[gnt*16 + ln] + bhh[gnt*16 + ln];
    }

    for (int it = 0; it < FEAT_ITERS; ++it) {
      const int tile = it * 256 + B;           // iteration-major: it covers
      const long r0  = (long)tile * 64;        //   t in [64*it, 64*it+64)
      float* zb = (tile >= 4092) ? (yz + (r0 - 261888) * H_DIM)
                                 : (Z + r0 * H_DIM);
      {
        const float4* x4 = (const float4*)x;
#pragma unroll
        for (int p = 0; p < 2; ++p) {
          int f = tid + p * 512;
          int row = f >> 4, kc = (f & 15) * 4;
          float4 v = x4[r0 * 16 + f];
          half4 s = { (_Float16)v.x, (_Float16)v.y, (_Float16)v.z, (_Float16)v.w };
          *(half4*)&xt_l[row * XT_S + kc] = s;
        }
      }
      barrier_lds_only();

      half8 a1[2];
#pragma unroll
      for (int kf = 0; kf < 2; ++kf)
        a1[kf] = *(const half8*)&xt_l[(rg*16 + ln) * XT_S + kf*32 + kg*8];

#pragma unroll
      for (int nt = 0; nt < 4; ++nt) {
        f32x4 acc = {0.f, 0.f, 0.f, 0.f};
#pragma unroll
        for (int kf = 0; kf < 2; ++kf)
          acc = __builtin_amdgcn_mfma_f32_16x16x32_f16(a1[kf], wxr[nt][kf], acc, 0, 0, 0);
#pragma unroll
        for (int c = 0; c < 4; ++c) {
          float v = fast_tanh(acc[c] + bx_r[nt]);
          fm_l[(rg*16 + kg*4 + c) * FM_S + (cg*4 + nt)*16 + ln] = (_Float16)v;
        }
      }
      barrier_lds_only();   // cross-cg: stage2 reads full fm rows

      half8 a2[4];
#pragma unroll
      for (int kf = 0; kf < 4; ++kf)
        a2[kf] = *(const half8*)&fm_l[(rg*16 + ln) * FM_S + kf*32 + kg*8];

#pragma unroll
      for (int nt = 0; nt < 4; ++nt) {
        const int gnt = cg*4 + nt;
        f32x4 acc = { b2_r[nt], b2_r[nt], b2_r[nt], b2_r[nt] };
#pragma unroll
        for (int kf = 0; kf < 4; ++kf) {
          half8 bf = *(const half8*)&wi_l[(gnt*16 + ln) * WI_S + kf*32 + kg*8];
          acc = __builtin_amdgcn_mfma_f32_16x16x32_f16(a2[kf], bf, acc, 0, 0, 0);
        }
#pragma unroll
        for (int c = 0; c < 4; ++c)
          zb[(rg*16 + kg*4 + c) * H_DIM + gnt*16 + ln] = acc[c];
      }
      barrier_lds_only();   // protect xt_l/fm_l for next iteration

      if ((tid & 63) == 0) {           // one signal per wave: release + count
        __threadfence();
        atomicAdd(&iterCnt[it], 1);
      }
    }
  }
}

// ---------------------------------------------------------------------------
// Kernel 3 (f16 MFMA): y = tanh(h Wh^T + bh) Wg^T + bg.  [R0 verbatim]
// ---------------------------------------------------------------------------
#define TILE_R 64
#define TPW    8
#define HM_S   136
#define WH_S   136

__global__ __launch_bounds__(256) void k_out_mfma(
    const float* __restrict__ Zh, const float* __restrict__ Wh,
    const float* __restrict__ bh, const float* __restrict__ Wg,
    const float* __restrict__ bg, float* __restrict__ y)
{
  __shared__ __align__(16) _Float16 wh_l[128 * WH_S];    // 34816 B
  __shared__ __align__(16) _Float16 hm_l[TILE_R * HM_S]; // 17408 B

  const int tid = threadIdx.x;
  const int l   = tid & 63;
  const int wv  = tid >> 6;
  const int ln  = l & 15;
  const int kg  = l >> 4;

  {
    const float4* wg4 = (const float4*)Wh;
#pragma unroll
    for (int p = 0; p < 16; ++p) {
      int f = tid + p * 256;
      int row = f >> 5, kc = (f & 31) * 4;
      float4 v = wg4[f];
      half4 s = { (_Float16)v.x, (_Float16)v.y, (_Float16)v.z, (_Float16)v.w };
      *(half4*)&wh_l[row * WH_S + kc] = s;
    }
  }

  half8 wg_r[4][4];
#pragma unroll
  for (int nt2 = 0; nt2 < 4; ++nt2)
#pragma unroll
    for (int ks = 0; ks < 4; ++ks) {
      const float* wp = Wg + (nt2*16 + ln) * H_DIM + ks*32 + kg*8;
      wg_r[nt2][ks] = pack_h8(*(const float4*)wp, *(const float4*)(wp + 4));
    }

  float bh_r[8], bg_r[4];
#pragma unroll
  for (int nt = 0; nt < 8; ++nt) bh_r[nt] = bh[nt*16 + ln];
#pragma unroll
  for (int nt2 = 0; nt2 < 4; ++nt2) bg_r[nt2] = bg[nt2*16 + ln];

  for (int it = 0; it < TPW; ++it) {
    const int tile = blockIdx.x * TPW + it;
    const long r0  = (long)tile * TILE_R;
    const bool zero = (tile < 4);        // rows < 256 -> t==0 -> h = 0

    {
      const float4* hg = (const float4*)(Zh + (r0 - 256) * H_DIM);
#pragma unroll
      for (int p = 0; p < 8; ++p) {
        int f = tid + p * 256;
        int row = f >> 5, kc = (f & 31) * 4;
        float4 v;
        if (zero) { v.x = v.y = v.z = v.w = 0.f; } else { v = hg[f]; }
        half4 s = { (_Float16)v.x, (_Float16)v.y, (_Float16)v.z, (_Float16)v.w };
        *(half4*)&hm_l[row * HM_S + kc] = s;
      }
    }
    barrier_lds_only();

    half8 af[4];
#pragma unroll
    for (int ks = 0; ks < 4; ++ks)
      af[ks] = *(const half8*)&hm_l[(wv*16 + ln) * HM_S + ks*32 + kg*8];

#pragma unroll
    for (int nt = 0; nt < 8; ++nt) {
      f32x4 acc = {0.f, 0.f, 0.f, 0.f};
#pragma unroll
      for (int ks = 0; ks < 4; ++ks) {
        half8 bf = *(const half8*)&wh_l[(nt*16 + ln) * WH_S + ks*32 + kg*8];
        acc = __builtin_amdgcn_mfma_f32_16x16x32_f16(af[ks], bf, acc, 0, 0, 0);
      }
#pragma unroll
      for (int c = 0; c < 4; ++c) {
        float val = fast_tanh(acc[c] + bh_r[nt]);
        hm_l[(wv*16 + kg*4 + c) * HM_S + nt*16 + ln] = (_Float16)val;
      }
    }

    half8 a2[4];
#pragma unroll
    for (int ks = 0; ks < 4; ++ks)
      a2[ks] = *(const half8*)&hm_l[(wv*16 + ln) * HM_S + ks*32 + kg*8];

#pragma unroll
    for (int nt2 = 0; nt2 < 4; ++nt2) {
      f32x4 acc2 = { bg_r[nt2], bg_r[nt2], bg_r[nt2], bg_r[nt2] };
#pragma unroll
      for (int ks = 0; ks < 4; ++ks)
        acc2 = __builtin_amdgcn_mfma_f32_16x16x32_f16(a2[ks], wg_r[nt2][ks],
                                                      acc2, 0, 0, 0);
#pragma unroll
      for (int c = 0; c < 4; ++c)
        y[(r0 + wv*16 + kg*4 + c) * D_IN + nt2*16 + ln] = acc2[c];
    }
    barrier_lds_only();
  }
}

extern "C" void kernel_launch(void* const* d_in, const int* in_sizes, int n_in,
                              void* d_out, int out_size, void* d_ws, size_t ws_size,
                              hipStream_t stream) {
  const float* x   = (const float*)d_in[0];
  const float* Wx  = (const float*)d_in[1];
  const float* bx  = (const float*)d_in[2];
  const float* Wih = (const float*)d_in[3];
  const float* bih = (const float*)d_in[4];
  const float* Whh = (const float*)d_in[5];
  const float* bhh = (const float*)d_in[6];
  const float* Wh  = (const float*)d_in[7];
  const float* bh  = (const float*)d_in[8];
  const float* Wg  = (const float*)d_in[9];
  const float* bg  = (const float*)d_in[10];
  float* Z = (float*)d_ws;              // T*B*H*4 = 134,217,728 B
  float* y = (float*)d_out;             // also: feat's z_1023 scratch + flags home in Z tail

  k_init      <<<1,   64,  0, stream>>>(Z);
  k_feat_scan <<<512, 512, 0, stream>>>(x, Wx, bx, Wih, bih, Whh, bhh, Z, y);
  k_out_mfma  <<<512, 256, 0, stream>>>(Z, Wh, bh, Wg, bg, y);
}